// Round 1
// 429.405 us; speedup vs baseline: 1.0227x; 1.0227x over previous
//
#include <hip/hip_runtime.h>

// ---------------------------------------------------------------------------
// Sliding-window GQA attention block.
// R4: O-projection GEMM moved from the m97 128x128/2-barrier structure
// (673 TF, MfmaUtil 29%, 8.4M bank conflicts) to the m201 256x256 8-phase
// template: BK=64, 8 waves (2Mx4N), 128 KiB LDS double-buffer, st_16x32
// XOR swizzle (pre-swizzled global source since global_load_lds writes
// linearly; swizzled ds_read addresses), raw s_barrier + counted vmcnt(4)
// (never drained to 0 in the main loop), setprio(1) around each 16-MFMA
// quadrant cluster. Schedule safety: a region's last ds_read drains at its
// phase's lgkmcnt(0) before that phase's end barrier; the overwriting stage
// is issued only after a later barrier. Tile T halves staged at
// (T-2).ph3/ph4 + (T-1).ph1/ph2; vmcnt(4) at ph4 guarantees tile t+1 landed.
// Everything else unchanged from R3.
// ---------------------------------------------------------------------------

typedef __bf16 bf16x8 __attribute__((ext_vector_type(8)));
typedef float f32x4 __attribute__((ext_vector_type(4)));
typedef int v8i __attribute__((ext_vector_type(8)));

__device__ __forceinline__ unsigned short f2bf(float f) {
  unsigned int u = __float_as_uint(f);
  u += 0x7fffu + ((u >> 16) & 1u);   // RNE
  return (unsigned short)(u >> 16);
}

__device__ __forceinline__ f32x4 mfma16(bf16x8 a, bf16x8 b, f32x4 c) {
  return __builtin_amdgcn_mfma_f32_16x16x32_bf16(a, b, c, 0, 0, 0);
}

// async global->LDS, 16B per lane, deposits at wave-uniform base + lane*16
__device__ __forceinline__ void async16(void* lds, const void* g) {
  __builtin_amdgcn_global_load_lds(
      (__attribute__((address_space(1))) unsigned int*)g,
      (__attribute__((address_space(3))) unsigned int*)lds, 16, 0, 0);
}

// --------------------------- conversion kernels ----------------------------

// hidden f32 -> bf16 (for V-proj) AND fp8 e4m3 (for QK-proj)
__global__ __launch_bounds__(256) void convert_h_kernel(
    const float* __restrict__ src, unsigned short* __restrict__ dbf,
    unsigned char* __restrict__ d8, int n) {
  int i = (blockIdx.x * 256 + threadIdx.x) * 4;
  if (i < n) {
    float4 f = *(const float4*)(src + i);
    ushort4 o;
    o.x = f2bf(f.x); o.y = f2bf(f.y); o.z = f2bf(f.z); o.w = f2bf(f.w);
    *(ushort4*)(dbf + i) = o;
    int p = __builtin_amdgcn_cvt_pk_fp8_f32(f.x, f.y, 0, 0);
    p = __builtin_amdgcn_cvt_pk_fp8_f32(f.z, f.w, p, 1);
    *(unsigned int*)(d8 + i) = p;
  }
}

// src f32 [K][N] row-major  ->  dst bf16 [N][K] row-major (transposed)
__global__ __launch_bounds__(256) void transpose_convert_kernel(
    const float* __restrict__ src, unsigned short* __restrict__ dst,
    int K, int N) {
  __shared__ unsigned short T[64 * 72];
  int kb = blockIdx.y * 64, nb = blockIdx.x * 64;
  int t = threadIdx.x;
  for (int u = t; u < 1024; u += 256) {
    int r = u >> 4, s = u & 15;
    float4 f = *(const float4*)(src + (size_t)(kb + r) * N + nb + s * 4);
    ushort4 o;
    o.x = f2bf(f.x); o.y = f2bf(f.y); o.z = f2bf(f.z); o.w = f2bf(f.w);
    *(ushort4*)&T[r * 72 + s * 4] = o;
  }
  __syncthreads();
  for (int u = t; u < 1024; u += 256) {
    int orow = u >> 4, s = u & 15;
    ushort4 o;
    o.x = T[(s * 4 + 0) * 72 + orow];
    o.y = T[(s * 4 + 1) * 72 + orow];
    o.z = T[(s * 4 + 2) * 72 + orow];
    o.w = T[(s * 4 + 3) * 72 + orow];
    *(ushort4*)(dst + (size_t)(nb + orow) * K + kb + s * 4) = o;
  }
}

// src f32 [K][N] row-major -> dst fp8 e4m3 [N][K] (transposed)
__global__ __launch_bounds__(256) void transpose_convert_fp8_kernel(
    const float* __restrict__ src, unsigned char* __restrict__ dst,
    int K, int N) {
  __shared__ unsigned short T[64 * 72];
  int kb = blockIdx.y * 64, nb = blockIdx.x * 64;
  int t = threadIdx.x;
  for (int u = t; u < 1024; u += 256) {
    int r = u >> 4, s = u & 15;
    float4 f = *(const float4*)(src + (size_t)(kb + r) * N + nb + s * 4);
    ushort4 o;
    o.x = f2bf(f.x); o.y = f2bf(f.y); o.z = f2bf(f.z); o.w = f2bf(f.w);
    *(ushort4*)&T[r * 72 + s * 4] = o;
  }
  __syncthreads();
  for (int u = t; u < 1024; u += 256) {
    int orow = u >> 4, s = u & 15;
    float f0 = __uint_as_float((unsigned int)T[(s * 4 + 0) * 72 + orow] << 16);
    float f1 = __uint_as_float((unsigned int)T[(s * 4 + 1) * 72 + orow] << 16);
    float f2 = __uint_as_float((unsigned int)T[(s * 4 + 2) * 72 + orow] << 16);
    float f3 = __uint_as_float((unsigned int)T[(s * 4 + 3) * 72 + orow] << 16);
    int p = __builtin_amdgcn_cvt_pk_fp8_f32(f0, f1, 0, 0);
    p = __builtin_amdgcn_cvt_pk_fp8_f32(f2, f3, p, 1);
    *(unsigned int*)&dst[(size_t)(nb + orow) * K + kb + s * 4] = p;
  }
}

// V slice of QKV [8192 rows][cols 2560..3071] -> VTg [512][8192] bf16.
__global__ __launch_bounds__(256) void vtrans_kernel(
    const unsigned short* __restrict__ QKV, unsigned short* __restrict__ VTg) {
  int flat = blockIdx.x * 256 + threadIdx.x;
  int c = flat & 511;
  int s0 = (flat >> 9) * 8;
  unsigned short tmp[8];
  #pragma unroll
  for (int j = 0; j < 8; ++j)
    tmp[j] = QKV[(size_t)(s0 + j) * 3072 + 2560 + c];
  *(uint4*)&VTg[(size_t)c * 8192 + s0] = *(uint4*)tmp;
}

// ---------------------------- bf16 GEMM (V-proj) ---------------------------
// C[M,:] (ldc) = A[M,K] * BT[N,K]^T ; m97 structure, 128x128 tile, BK=32.

template <bool F32OUT>
__global__ __launch_bounds__(256) void gemm_bt_kernel(
    const unsigned short* __restrict__ A, const unsigned short* __restrict__ BT,
    void* __restrict__ Cp, int M, int ldc, int K) {
  __shared__ unsigned short As[128 * 32];
  __shared__ unsigned short Bs[128 * 32];
  int mb = blockIdx.y * 128, nb = blockIdx.x * 128;
  int tid = threadIdx.x;
  int lane = tid & 63, wv = tid >> 6;
  int wrow = wv >> 1, wcol = wv & 1;
  int lr = lane >> 2, ls = lane & 3;
  int fr = lane & 15, fg = lane >> 4;
  f32x4 acc[4][4] = {};
  for (int k0 = 0; k0 < K; k0 += 32) {
    __syncthreads();
    #pragma unroll
    for (int r = 0; r < 2; ++r) {
      int s = wv * 2 + r;
      async16(&As[s * 512], &A[(size_t)(mb + s * 16 + lr) * K + k0 + ls * 8]);
      async16(&Bs[s * 512], &BT[(size_t)(nb + s * 16 + lr) * K + k0 + ls * 8]);
    }
    __syncthreads();
    bf16x8 a[4], b[4];
    #pragma unroll
    for (int rt = 0; rt < 4; ++rt)
      a[rt] = *(const bf16x8*)&As[(wrow * 64 + rt * 16 + fr) * 32 + fg * 8];
    #pragma unroll
    for (int ct = 0; ct < 4; ++ct)
      b[ct] = *(const bf16x8*)&Bs[(wcol * 64 + ct * 16 + fr) * 32 + fg * 8];
    #pragma unroll
    for (int rt = 0; rt < 4; ++rt)
      #pragma unroll
      for (int ct = 0; ct < 4; ++ct)
        acc[rt][ct] = mfma16(a[rt], b[ct], acc[rt][ct]);
  }
  #pragma unroll
  for (int rt = 0; rt < 4; ++rt)
    #pragma unroll
    for (int ct = 0; ct < 4; ++ct)
      #pragma unroll
      for (int i = 0; i < 4; ++i) {
        int row = mb + wrow * 64 + rt * 16 + fg * 4 + i;
        int col = nb + wcol * 64 + ct * 16 + fr;
        if constexpr (F32OUT)
          ((float*)Cp)[(size_t)row * ldc + col] = acc[rt][ct][i];
        else
          ((unsigned short*)Cp)[(size_t)row * ldc + col] = f2bf(acc[rt][ct][i]);
      }
}

// ------------------- 8-phase 256x256 bf16 GEMM (O-proj) --------------------
// C f32 [M][ldc] = A bf16 [M][K] * BT bf16 [N][K]^T.  M%256==0, N%256==0,
// K%64==0, K>=128.  Grid: (N/256, M/256), 512 threads.
//
// LDS (128 KiB): per buffer, A tile [256][64] bf16 at +0, B tile at +32768.
// st_16x32 swizzle: phys_byte = logical_byte ^ ((logical_byte>>9 & 1) << 5).
// Writes are linear (global_load_lds); the SOURCE global address is
// pre-swizzled per lane (involution), reads apply the same XOR.
//
// Quadrant order per K-tile: (r0,c0) (r1,c0) (r1,c1) (r0,c1).
// Stage slots: ph1 -> tile(t+1).A-r0half (buf nxt), ph2 -> tile(t+1).B-c1half,
// ph3 -> tile(t+2).B-c0half (buf cur), ph4 -> tile(t+2).A-r1half.
// vmcnt(4) at ph4 => tile t+1 fully landed; tile t+2's 2 halves stay in
// flight across the barrier (counted, never 0).

__global__ __launch_bounds__(512, 2) void gemm8p_oproj_kernel(
    const unsigned short* __restrict__ A, const unsigned short* __restrict__ BT,
    float* __restrict__ C, int ldc, int K) {
  __shared__ unsigned char lds[131072];
  const int mb = blockIdx.y * 256, nb = blockIdx.x * 256;
  const int tid = threadIdx.x;
  const int lane = tid & 63, wv = tid >> 6;
  const int wm = wv >> 2, wn = wv & 3;       // 2 x 4 wave grid
  const int fr = lane & 15, fg = lane >> 4;
  const int xr = (fr & 4) ? 32 : 0;          // read-side swizzle XOR
  const int a_base = (wm * 128 + fr) * 128 + ((fg * 16) ^ xr);
  const int b_base = (wn * 64 + fr) * 128 + ((fg * 16) ^ xr);
  // staging: lane's pre-swizzled logical offset within its 1024B chunk
  const int lsw = (lane * 16) ^ (lane & 32);
  const int lrow = lsw >> 7, lcol = (lsw & 127) >> 1;
  const int NT = K >> 6;

  f32x4 acc[8][4] = {};
  bf16x8 aF[4][2], bF[2][2];

#define FENCE_ asm volatile("" ::: "memory")
#define BAR_ { FENCE_; __builtin_amdgcn_s_barrier(); FENCE_; }
#define LGKM0_ asm volatile("s_waitcnt lgkmcnt(0)" ::: "memory")
#define STAGE_A_(BUFI, T, HALF)                                              \
  { _Pragma("unroll")                                                        \
    for (int l = 0; l < 2; ++l) {                                            \
      int cc = wv * 2 + l;                                                   \
      int rb = (cc >> 3) * 128 + (HALF) * 64 + (cc & 7) * 8;                 \
      async16(lds + (BUFI) * 65536 + rb * 128,                               \
              A + (size_t)(mb + rb + lrow) * K + (T) * 64 + lcol);           \
    } }
#define STAGE_B_(BUFI, T, HALF)                                              \
  { _Pragma("unroll")                                                        \
    for (int l = 0; l < 2; ++l) {                                            \
      int cc = wv * 2 + l;                                                   \
      int rb = (cc >> 2) * 64 + (HALF) * 32 + (cc & 3) * 8;                  \
      async16(lds + (BUFI) * 65536 + 32768 + rb * 128,                       \
              BT + (size_t)(nb + rb + lrow) * K + (T) * 64 + lcol);          \
    } }
#define LOAD_A_(HALF)                                                        \
  { _Pragma("unroll")                                                        \
    for (int q = 0; q < 4; ++q)                                              \
      _Pragma("unroll")                                                      \
      for (int kk = 0; kk < 2; ++kk)                                         \
        aF[q][kk] =                                                          \
            *(const bf16x8*)&Ab_[a_base + ((HALF)*4 + q) * 2048 + kk * 64]; }
#define LOAD_B_(HALF)                                                        \
  { _Pragma("unroll")                                                        \
    for (int c2 = 0; c2 < 2; ++c2)                                           \
      _Pragma("unroll")                                                      \
      for (int kk = 0; kk < 2; ++kk)                                         \
        bF[c2][kk] =                                                         \
            *(const bf16x8*)&Bb_[b_base + ((HALF)*2 + c2) * 2048 + kk * 64]; }
#define MFMA_(RT0, CT0)                                                      \
  { __builtin_amdgcn_s_setprio(1);                                           \
    _Pragma("unroll")                                                        \
    for (int q = 0; q < 4; ++q)                                              \
      _Pragma("unroll")                                                      \
      for (int c2 = 0; c2 < 2; ++c2) {                                       \
        acc[(RT0) + q][(CT0) + c2] =                                         \
            mfma16(aF[q][0], bF[c2][0], acc[(RT0) + q][(CT0) + c2]);         \
        acc[(RT0) + q][(CT0) + c2] =                                         \
            mfma16(aF[q][1], bF[c2][1], acc[(RT0) + q][(CT0) + c2]);         \
      }                                                                      \
    __builtin_amdgcn_s_setprio(0); }

  // prologue: tile0 complete + tile1 {B-c0 half, A-r1 half}
  STAGE_A_(0, 0, 0); STAGE_A_(0, 0, 1); STAGE_B_(0, 0, 0); STAGE_B_(0, 0, 1);
  STAGE_B_(1, 1, 0); STAGE_A_(1, 1, 1);
  asm volatile("s_waitcnt vmcnt(4)" ::: "memory");   // tile0 landed
  BAR_;

  for (int t = 0; t < NT; ++t) {
    const int cur = t & 1, nxt = cur ^ 1;
    const unsigned char* Ab_ = lds + cur * 65536;
    const unsigned char* Bb_ = Ab_ + 32768;
    // ---- phase 1: quadrant r0 x c0 (12 ds_reads)
    LOAD_A_(0); LOAD_B_(0);
    if (t + 1 < NT) STAGE_A_(nxt, t + 1, 0);
    BAR_; LGKM0_;
    MFMA_(0, 0);
    BAR_;
    // ---- phase 2: quadrant r1 x c0 (8 ds_reads, bF reused)
    LOAD_A_(1);
    if (t + 1 < NT) STAGE_B_(nxt, t + 1, 1);
    BAR_; LGKM0_;
    MFMA_(4, 0);
    BAR_;
    // ---- phase 3: quadrant r1 x c1 (4 ds_reads, aF reused)
    LOAD_B_(1);
    if (t + 2 < NT) STAGE_B_(cur, t + 2, 0);
    BAR_; LGKM0_;
    MFMA_(4, 2);
    BAR_;
    // ---- phase 4: quadrant r0 x c1 (8 ds_reads, bF reused)
    LOAD_A_(0);
    if (t + 2 < NT) STAGE_A_(cur, t + 2, 1);
    BAR_; LGKM0_;
    MFMA_(0, 2);
    asm volatile("s_waitcnt vmcnt(4)" ::: "memory"); // tile t+1 landed
    BAR_;
  }

  #pragma unroll
  for (int rt = 0; rt < 8; ++rt)
    #pragma unroll
    for (int ct = 0; ct < 4; ++ct)
      #pragma unroll
      for (int i = 0; i < 4; ++i) {
        int row = mb + wm * 128 + rt * 16 + fg * 4 + i;
        int col = nb + wn * 64 + ct * 16 + fr;
        C[(size_t)row * ldc + col] = acc[rt][ct][i];
      }
#undef FENCE_
#undef BAR_
#undef LGKM0_
#undef STAGE_A_
#undef STAGE_B_
#undef LOAD_A_
#undef LOAD_B_
#undef MFMA_
}

// ---------------------------- fp8 GEMM (Q/K proj) --------------------------
// C bf16 = A8[M,K] * B8T[N,K]^T, unit-scale MX fp8, 16x16x128 MFMA, BK=128.

__global__ __launch_bounds__(256) void gemm_qk_fp8_kernel(
    const unsigned char* __restrict__ A8, const unsigned char* __restrict__ B8,
    unsigned short* __restrict__ C, int M, int ldc, int K) {
  __shared__ unsigned char As[128 * 144];
  __shared__ unsigned char Bs[128 * 144];
  int mb = blockIdx.y * 128, nb = blockIdx.x * 128;
  int tid = threadIdx.x;
  int lane = tid & 63, wv = tid >> 6;
  int wrow = wv >> 1, wcol = wv & 1;
  int fr = lane & 15, fg = lane >> 4;
  int srow = tid >> 1, shalf = (tid & 1) * 64;   // staging: 64B half-rows
  f32x4 acc[4][4] = {};
  for (int k0 = 0; k0 < K; k0 += 128) {
    __syncthreads();
    #pragma unroll
    for (int j = 0; j < 4; ++j) {
      *(uint4*)&As[srow * 144 + shalf + j * 16] =
          *(const uint4*)&A8[(size_t)(mb + srow) * K + k0 + shalf + j * 16];
      *(uint4*)&Bs[srow * 144 + shalf + j * 16] =
          *(const uint4*)&B8[(size_t)(nb + srow) * K + k0 + shalf + j * 16];
    }
    __syncthreads();
    v8i a[4], b[4];
    #pragma unroll
    for (int rt = 0; rt < 4; ++rt) {
      int off = (wrow * 64 + rt * 16 + fr) * 144 + fg * 32;
      ((uint4*)&a[rt])[0] = *(const uint4*)&As[off];
      ((uint4*)&a[rt])[1] = *(const uint4*)&As[off + 16];
    }
    #pragma unroll
    for (int ct = 0; ct < 4; ++ct) {
      int off = (wcol * 64 + ct * 16 + fr) * 144 + fg * 32;
      ((uint4*)&b[ct])[0] = *(const uint4*)&Bs[off];
      ((uint4*)&b[ct])[1] = *(const uint4*)&Bs[off + 16];
    }
    #pragma unroll
    for (int rt = 0; rt < 4; ++rt)
      #pragma unroll
      for (int ct = 0; ct < 4; ++ct)
        acc[rt][ct] = __builtin_amdgcn_mfma_scale_f32_16x16x128_f8f6f4(
            a[rt], b[ct], acc[rt][ct], 0, 0,
            0, 0x7F7F7F7F,   // A scales: e8m0 127 = 1.0
            0, 0x7F7F7F7F);  // B scales
  }
  #pragma unroll
  for (int rt = 0; rt < 4; ++rt)
    #pragma unroll
    for (int ct = 0; ct < 4; ++ct)
      #pragma unroll
      for (int i = 0; i < 4; ++i) {
        int row = mb + wrow * 64 + rt * 16 + fg * 4 + i;
        int col = nb + wcol * 64 + ct * 16 + fr;
        C[(size_t)row * ldc + col] = f2bf(acc[rt][ct][i]);
      }
}

// ----------------------------- attention -----------------------------------
// Unchanged from R2. 4 heads/block, 64-key chunks, fixed-max softmax,
// bank-uniform strides.

#define SCALE_L2E 0.0112710027f   // log2(e)/128

__global__ __launch_bounds__(512, 2) void attn_kernel(
    const unsigned short* __restrict__ QKV,
    const unsigned short* __restrict__ VTg,
    unsigned short* __restrict__ O) {
  __shared__ unsigned short Ks[64 * 136];
  __shared__ unsigned short VTs[128 * 72];
  __shared__ unsigned short Ps[8 * 32 * 72];
  const int g = blockIdx.y;
  const int qs = blockIdx.x * 64;
  const int tid = threadIdx.x;
  const int lane = tid & 63, w = tid >> 6;
  const int fr = lane & 15, fg = lane >> 4;
  const int hl = w & 3, qh = w >> 2;
  const int h = g * 4 + hl;
  const int kcol = 2048 + g * 128;
  unsigned short* Pw = &Ps[w * 32 * 72];

  bf16x8 qf[2][4];
  #pragma unroll
  for (int qt = 0; qt < 2; ++qt) {
    int qrow = qs + qh * 32 + qt * 16 + fr;
    #pragma unroll
    for (int kk = 0; kk < 4; ++kk)
      qf[qt][kk] = *(const bf16x8*)&QKV[(size_t)qrow * 3072 + h * 128 + kk * 32 + fg * 8];
  }
  f32x4 o_acc[2][8] = {};
  float l_part[2][4] = {};
  const int kb0 = qs >= 512 ? qs - 512 : 0;
  for (int kb = kb0; kb <= qs; kb += 64) {
    __syncthreads();
    #pragma unroll
    for (int it = 0; it < 2; ++it) {
      int u = tid + it * 512;
      int key = u >> 4, seg = u & 15;
      *(uint4*)&Ks[key * 136 + seg * 8] =
          *(const uint4*)&QKV[(size_t)(kb + key) * 3072 + kcol + seg * 8];
    }
    #pragma unroll
    for (int it = 0; it < 2; ++it) {
      int u = tid + it * 512;
      int d = u >> 3, seg = u & 7;
      *(uint4*)&VTs[d * 72 + seg * 8] =
          *(const uint4*)&VTg[(size_t)(g * 128 + d) * 8192 + kb + seg * 8];
    }
    __syncthreads();
    f32x4 s_acc[2][4] = {};
    #pragma unroll
    for (int kt = 0; kt < 4; ++kt) {
      bf16x8 kf[4];
      #pragma unroll
      for (int kk = 0; kk < 4; ++kk)
        kf[kk] = *(const bf16x8*)&Ks[(kt * 16 + fr) * 136 + kk * 32 + fg * 8];
      #pragma unroll
      for (int qt = 0; qt < 2; ++qt)
        #pragma unroll
        for (int kk = 0; kk < 4; ++kk)
          s_acc[qt][kt] = mfma16(qf[qt][kk], kf[kk], s_acc[qt][kt]);
    }
    const bool edge = (kb > qs - 64) || (kb < qs - 448);
    #pragma unroll
    for (int qt = 0; qt < 2; ++qt)
      #pragma unroll
      for (int kt = 0; kt < 4; ++kt)
        #pragma unroll
        for (int i = 0; i < 4; ++i) {
          float p = exp2f(s_acc[qt][kt][i] * SCALE_L2E);
          if (edge) {
            int kg = kb + kt * 16 + fr;
            int qg = qs + qh * 32 + qt * 16 + fg * 4 + i;
            if (kg > qg || kg < qg - 511) p = 0.f;
          }
          l_part[qt][i] += p;
          Pw[(qt * 16 + fg * 4 + i) * 72 + kt * 16 + fr] = f2bf(p);
        }
    bf16x8 af[2][2];
    #pragma unroll
    for (int qt = 0; qt < 2; ++qt)
      #pragma unroll
      for (int kf2 = 0; kf2 < 2; ++kf2)
        af[qt][kf2] = *(const bf16x8*)&Pw[(qt * 16 + fr) * 72 + kf2 * 32 + fg * 8];
    #pragma unroll
    for (int dt = 0; dt < 8; ++dt) {
      bf16x8 vf[2];
      #pragma unroll
      for (int kf2 = 0; kf2 < 2; ++kf2)
        vf[kf2] = *(const bf16x8*)&VTs[(dt * 16 + fr) * 72 + kf2 * 32 + fg * 8];
      #pragma unroll
      for (int qt = 0; qt < 2; ++qt)
        #pragma unroll
        for (int kf2 = 0; kf2 < 2; ++kf2)
          o_acc[qt][dt] = mfma16(af[qt][kf2], vf[kf2], o_acc[qt][dt]);
    }
  }
  #pragma unroll
  for (int qt = 0; qt < 2; ++qt)
    #pragma unroll
    for (int i = 0; i < 4; ++i) {
      float s = l_part[qt][i];
      s += __shfl_xor(s, 1); s += __shfl_xor(s, 2);
      s += __shfl_xor(s, 4); s += __shfl_xor(s, 8);
      l_part[qt][i] = 1.f / s;
    }
  #pragma unroll
  for (int qt = 0; qt < 2; ++qt)
    #pragma unroll
    for (int dt = 0; dt < 8; ++dt)
      #pragma unroll
      for (int i = 0; i < 4; ++i) {
        int row = qs + qh * 32 + qt * 16 + fg * 4 + i;
        O[(size_t)row * 2048 + h * 128 + dt * 16 + fr] =
            f2bf(o_acc[qt][dt][i] * l_part[qt][i]);
      }
}

// ------------------------------ launcher -----------------------------------

extern "C" void kernel_launch(void* const* d_in, const int* in_sizes, int n_in,
                              void* d_out, int out_size, void* d_ws, size_t ws_size,
                              hipStream_t stream) {
  const float* h  = (const float*)d_in[0];
  const float* Wq = (const float*)d_in[1];
  const float* Wk = (const float*)d_in[2];
  const float* Wv = (const float*)d_in[3];
  const float* Wo = (const float*)d_in[4];
  float* out = (float*)d_out;
  char* ws = (char*)d_ws;
  const int S = 8192, D = 2048;
  const size_t MB = 1024 * 1024;

  // workspace (byte offsets), 101 MB peak, time-multiplexed:
  unsigned short* QKV = (unsigned short*)(ws);             // [8192][3072] bf16, 48 MB
  unsigned short* hbf = (unsigned short*)(ws + 48 * MB);   // [8192][2048] bf16, 32 MB
  unsigned short* Ab  = hbf;                               // attn out (hbf dead after V gemm)
  unsigned char*  h8  = (unsigned char*)(ws + 80 * MB);    // [8192][2048] fp8, 16 MB
  unsigned short* VTg = (unsigned short*)(ws + 80 * MB);   // [512][8192] bf16 (h8 dead)
  unsigned short* WoT = (unsigned short*)(ws + 88 * MB);   // [2048][2048] bf16 (h8 dead)
  unsigned char*  W8  = (unsigned char*)(ws + 96 * MB);    // [2560][2048] fp8, 5 MB
  unsigned short* WvT = (unsigned short*)(ws + 96 * MB);   // [512][2048] bf16 (W8 dead)

  convert_h_kernel<<<16384, 256, 0, stream>>>(h, hbf, h8, S * D);
  transpose_convert_fp8_kernel<<<dim3(32, 32), 256, 0, stream>>>(Wq, W8, D, 2048);
  transpose_convert_fp8_kernel<<<dim3(8, 32), 256, 0, stream>>>(
      Wk, W8 + (size_t)2048 * 2048, D, 512);
  gemm_qk_fp8_kernel<<<dim3(20, 64), 256, 0, stream>>>(h8, W8, QKV, S, 3072, D);

  transpose_convert_kernel<<<dim3(8, 32), 256, 0, stream>>>(Wv, WvT, D, 512);
  gemm_bt_kernel<false><<<dim3(4, 64), 256, 0, stream>>>(hbf, WvT, QKV + 2560, S, 3072, D);

  vtrans_kernel<<<2048, 256, 0, stream>>>(QKV, VTg);
  transpose_convert_kernel<<<dim3(32, 32), 256, 0, stream>>>(Wo, WoT, D, 2048);
  attn_kernel<<<dim3(128, 4), 512, 0, stream>>>(QKV, VTg, Ab);
  gemm8p_oproj_kernel<<<dim3(8, 32), 512, 0, stream>>>(Ab, WoT, out, 2048, 2048);
}